// Round 12
// baseline (88.030 us; speedup 1.0000x reference)
//
#include <hip/hip_runtime.h>

#define NPROTO 512
#define NBLK 8
#define DB 128
#define DM 1024

#define IDX_OFF  8388608
#define VQ_OFF   8454144
#define CL_OFF   8454145

typedef unsigned short u16;
typedef __attribute__((ext_vector_type(8))) _Float16 f16x8;
typedef __attribute__((ext_vector_type(16))) float f32x16;

// ---- ws layout (bytes) ----
#define BH_B   0u
#define BL_B   1048576u
#define CN_B   2097152u
#define PART_B 2113536u
#define WS_NEED (PART_B + 8192u)

// ---- prep: split codes into 2 f16 planes in COALESCED MFMA-operand layout ----
// Bc[pl][m][kst][kg][pm][8]: flat idx = (((m*8+kst)*2+kg)*512 + pm)*8
__global__ __launch_bounds__(256) void vq_prep(const float* __restrict__ src,
                                               u16* __restrict__ hi,
                                               u16* __restrict__ lo,
                                               float* __restrict__ cn) {
    const int t  = threadIdx.x;
    const int p  = blockIdx.x * 32 + (t >> 3);   // global proto 0..4095
    const int g  = t & 7;                        // kst
    const int m  = p >> 9, pm = p & 511;
    const float* s = src + (size_t)p * DB + g * 16;
    float sq = 0.f;
    ushort4 h[4], l[4];
    #pragma unroll
    for (int j = 0; j < 4; ++j) {
        float4 v = *(const float4*)(s + j * 4);
        float x; _Float16 hf;
        #define S1(c, f) x = v.c; hf = (_Float16)x; h[j].f = __builtin_bit_cast(u16, hf); \
            hf = (_Float16)(x - (float)hf); l[j].f = __builtin_bit_cast(u16, hf); sq += x * x;
        S1(x, x) S1(y, y) S1(z, z) S1(w, w)
        #undef S1
    }
    const size_t o0 = ((size_t)((m * 8 + g) * 2 + 0) * 512 + pm) * 8;  // kg=0
    const size_t o1 = ((size_t)((m * 8 + g) * 2 + 1) * 512 + pm) * 8;  // kg=1
    *(uint4*)(hi + o0) = *(uint4*)&h[0];
    *(uint4*)(hi + o1) = *(uint4*)&h[2];
    *(uint4*)(lo + o0) = *(uint4*)&l[0];
    *(uint4*)(lo + o1) = *(uint4*)&l[2];
    sq += __shfl_xor(sq, 1, 64);
    sq += __shfl_xor(sq, 2, 64);
    sq += __shfl_xor(sq, 4, 64);
    if ((t & 7) == 0) cn[p] = sq;
}

__device__ __forceinline__ unsigned cvt2(float x, float y, unsigned& lo) {
    _Float16 hx = (_Float16)x, hy = (_Float16)y;
    _Float16 lx = (_Float16)(x - (float)hx), ly = (_Float16)(y - (float)hy);
    lo = (unsigned)__builtin_bit_cast(u16, lx) | ((unsigned)__builtin_bit_cast(u16, ly) << 16);
    return (unsigned)__builtin_bit_cast(u16, hx) | ((unsigned)__builtin_bit_cast(u16, hy) << 16);
}

// ================= fused MFMA main kernel (A-in-LDS, B-streamed) =============
// r11 post-mortem: latency-bound at 2 resident blocks/CU (Occ 26%); per-block
// prologue/epilogue latency dominates. r12: (256,4) -> 4 resident blocks
// (budget 128 >= 84 used, codegen unchanged); Ap kst-stride padded 64->66
// rows (bank off = 8g+4row: 2-way max) to kill staging-write conflicts.
__global__ __launch_bounds__(256, 4) void vq_fused(
        const float* __restrict__ q, const float* __restrict__ mem,
        const u16* __restrict__ bh, const u16* __restrict__ bl,
        const float* __restrict__ cn, float* __restrict__ out,
        float* __restrict__ partials) {
    __shared__ __align__(16) char smem0[16896];   // A_op (padded) / sval overlay
    __shared__ u16  sidxv[4][32][33];
    __shared__ float finalv[4][32];
    __shared__ int   finali[4][32];
    __shared__ float qn_lds[32];
    __shared__ int   bp[32];
    __shared__ float lossbuf[32];

    u16   (*Ap)[8][66][8] = (u16 (*)[8][66][8])smem0;    // [pl][kst][slot][8]
    float (*sval)[32][33] = (float (*)[32][33])smem0;    // overlay after loop

    const int t    = threadIdx.x;
    const int lane = t & 63;
    const int w    = t >> 6;          // 0..3
    const int col  = lane & 31;       // proto col == A row
    const int kg   = lane >> 5;       // k-group (8 elems)
    const int m    = blockIdx.y;
    const int bn0  = blockIdx.x * 32;

    // ---- stage A: 32 rows x 128 d f32 -> 2 f16 planes in lane-order LDS ----
    {
        const int row = t >> 3, g = t & 7;       // g == kst
        const float* src = q + (size_t)(bn0 + row) * DM + m * DB + g * 16;
        float4 v0 = ((const float4*)src)[0];
        float4 v1 = ((const float4*)src)[1];
        float4 v2 = ((const float4*)src)[2];
        float4 v3 = ((const float4*)src)[3];
        float sq = v0.x*v0.x+v0.y*v0.y+v0.z*v0.z+v0.w*v0.w
                 + v1.x*v1.x+v1.y*v1.y+v1.z*v1.z+v1.w*v1.w
                 + v2.x*v2.x+v2.y*v2.y+v2.z*v2.z+v2.w*v2.w
                 + v3.x*v3.x+v3.y*v3.y+v3.z*v3.z+v3.w*v3.w;
        unsigned l0,l1,l2,l3,l4,l5,l6,l7;
        unsigned h0 = cvt2(v0.x, v0.y, l0), h1 = cvt2(v0.z, v0.w, l1);
        unsigned h2 = cvt2(v1.x, v1.y, l2), h3 = cvt2(v1.z, v1.w, l3);
        unsigned h4 = cvt2(v2.x, v2.y, l4), h5 = cvt2(v2.z, v2.w, l5);
        unsigned h6 = cvt2(v3.x, v3.y, l6), h7 = cvt2(v3.z, v3.w, l7);
        // slot row   = kg0 slice (k = g*16 + 0..7)
        // slot row+32= kg1 slice (k = g*16 + 8..15)
        *(uint4*)&Ap[0][g][row][0]      = make_uint4(h0, h1, h2, h3);
        *(uint4*)&Ap[0][g][row + 32][0] = make_uint4(h4, h5, h6, h7);
        *(uint4*)&Ap[1][g][row][0]      = make_uint4(l0, l1, l2, l3);
        *(uint4*)&Ap[1][g][row + 32][0] = make_uint4(l4, l5, l6, l7);
        sq += __shfl_xor(sq, 1, 64);
        sq += __shfl_xor(sq, 2, 64);
        sq += __shfl_xor(sq, 4, 64);
        if (g == 0) qn_lds[row] = sq;
    }
    __syncthreads();

    // ---- main loop: wave w owns protos pbase..pbase+127, 4 chunks of 32 ----
    const int pbase = w * 128;
    const u16* bh_l = bh + ((size_t)(m * 16 + kg) * 512 + pbase + col) * 8;
    const u16* bl_l = bl + ((size_t)(m * 16 + kg) * 512 + pbase + col) * 8;

    float bestv[16]; int besti[16];
    #pragma unroll
    for (int r = 0; r < 16; ++r) { bestv[r] = 3.4e38f; besti[r] = 0; }

    #pragma unroll 1
    for (int c = 0; c < 4; ++c) {
        const float cnv = cn[m * NPROTO + pbase + c * 32 + col];
        const u16* bhc = bh_l + c * 256;
        const u16* blc = bl_l + c * 256;
        f32x16 aA, aB;
        #pragma unroll
        for (int r = 0; r < 16; ++r) { aA[r] = 0.f; aB[r] = 0.f; }
        #pragma unroll
        for (int kst = 0; kst < 8; ++kst) {
            f16x8 Bh = *(const f16x8*)(bhc + kst * 8192);
            f16x8 Bl = *(const f16x8*)(blc + kst * 8192);
            f16x8 Ah = *(const f16x8*)&Ap[0][kst][lane][0];
            f16x8 Al = *(const f16x8*)&Ap[1][kst][lane][0];
            aA = __builtin_amdgcn_mfma_f32_32x32x16_f16(Ah, Bh, aA, 0, 0, 0);
            aB = __builtin_amdgcn_mfma_f32_32x32x16_f16(Al, Bh, aB, 0, 0, 0);
            aB = __builtin_amdgcn_mfma_f32_32x32x16_f16(Ah, Bl, aB, 0, 0, 0);
        }
        const int ix = pbase + c * 32 + col;
        #pragma unroll
        for (int r = 0; r < 16; ++r) {
            float d = cnv - 2.0f * (aA[r] + aB[r]);
            if (d < bestv[r]) { bestv[r] = d; besti[r] = ix; }
        }
    }
    __syncthreads();   // A region now dead -> safe to overlay with sval

    // ---- scatter per-lane bests: C layout row=(r&3)+8*(r>>2)+4*kg, col ----
    #pragma unroll
    for (int r = 0; r < 16; ++r) {
        int row = (r & 3) + 8 * (r >> 2) + 4 * kg;
        sval[w][row][col]  = bestv[r];
        sidxv[w][row][col] = (u16)besti[r];
    }
    __syncthreads();

    // ---- per-wave column reduce ----
    {
        const int rrow = col, seg = kg;
        float bv = 3.4e38f; int bi = 0x7fffffff;
        #pragma unroll
        for (int c2 = 0; c2 < 16; ++c2) {
            float v = sval[w][rrow][seg * 16 + c2];
            int  ix = sidxv[w][rrow][seg * 16 + c2];
            if (v < bv || (v == bv && ix < bi)) { bv = v; bi = ix; }
        }
        float v2 = __shfl_xor(bv, 32, 64);
        int   i2 = __shfl_xor(bi, 32, 64);
        if (v2 < bv || (v2 == bv && i2 < bi)) { bv = v2; bi = i2; }
        if (kg == 0) { finalv[w][rrow] = bv; finali[w][rrow] = bi; }
    }
    __syncthreads();

    // ---- cross-wave combine + publish ----
    if (t < 32) {
        float bv = finalv[0][t]; int bi = finali[0][t];
        #pragma unroll
        for (int w2 = 1; w2 < 4; ++w2) {
            float v2 = finalv[w2][t]; int i2 = finali[w2][t];
            if (v2 < bv || (v2 == bv && i2 < bi)) { bv = v2; bi = i2; }
        }
        bp[t] = bi;
        out[(size_t)IDX_OFF + (size_t)(bn0 + t) * NBLK + m] =
            (float)(m * NPROTO + bi);
        lossbuf[t] = bv + qn_lds[t];   // true dist = qn - 2dot + cn
    }
    __syncthreads();

    // ---- gather winning code rows (exact f32 copy) ----
    {
        const int row = t >> 3, g = t & 7;
        const float* cv = mem + ((size_t)(m * NPROTO + bp[row])) * DB + g * 16;
        float* ov = out + (size_t)(bn0 + row) * DM + m * DB + g * 16;
        ((float4*)ov)[0] = ((const float4*)cv)[0];
        ((float4*)ov)[1] = ((const float4*)cv)[1];
        ((float4*)ov)[2] = ((const float4*)cv)[2];
        ((float4*)ov)[3] = ((const float4*)cv)[3];
    }
    if (t == 0) {
        float s = 0.f;
        #pragma unroll
        for (int i = 0; i < 32; ++i) s += lossbuf[i];
        partials[blockIdx.y * gridDim.x + blockIdx.x] = s;
    }
}

// ================= fallback f32 path (used only if ws too small) =============
__global__ __launch_bounds__(256) void vq_init(const float* __restrict__ mem,
                                               float* __restrict__ cn) {
    int p = blockIdx.x * 256 + threadIdx.x;
    const float* c = mem + (size_t)p * DB;
    float s = 0.f;
    #pragma unroll 8
    for (int k = 0; k < DB; k += 4) {
        float4 v = *(const float4*)(c + k);
        s += v.x * v.x + v.y * v.y + v.z * v.z + v.w * v.w;
    }
    cn[p] = s;
}

__global__ __launch_bounds__(256, 1) void vq_main_f32(const float* __restrict__ q,
                                                      const float* __restrict__ mem,
                                                      const float* __restrict__ cn,
                                                      float* __restrict__ out,
                                                      float* __restrict__ partials) {
    __shared__ float q_lds[128 * 132];
    __shared__ float c_lds[128 * 132];
    __shared__ float red[256];

    const int t    = threadIdx.x;
    const int tile = blockIdx.x;
    const int m    = blockIdx.y;
    const int tr   = t >> 4;
    const int tc   = t & 15;
    const int bn0  = tile * 128;

    const float* qbase = q + (size_t)bn0 * DM + m * DB;
    #pragma unroll
    for (int it = 0; it < 16; ++it) {
        int idx = it * 256 + t;
        int row = idx >> 5;
        int c4  = (idx & 31) << 2;
        *(float4*)&q_lds[row * 132 + c4] = *(const float4*)(qbase + (size_t)row * DM + c4);
    }

    float bestv[8]; int besti[8];
    #pragma unroll
    for (int i = 0; i < 8; ++i) { bestv[i] = 3.4e38f; besti[i] = 0; }
    const float* cbase = mem + (size_t)m * NPROTO * DB;

    for (int ch = 0; ch < 4; ++ch) {
        __syncthreads();
        const float* cb = cbase + (size_t)ch * 128 * DB;
        #pragma unroll
        for (int it = 0; it < 16; ++it) {
            int idx = it * 256 + t;
            int row = idx >> 5;
            int c4  = (idx & 31) << 2;
            *(float4*)&c_lds[row * 132 + c4] = *(const float4*)(cb + row * DB + c4);
        }
        __syncthreads();

        float acc[8][8];
        #pragma unroll
        for (int i = 0; i < 8; ++i)
            #pragma unroll
            for (int j = 0; j < 8; ++j) acc[i][j] = 0.f;

        for (int d4 = 0; d4 < DB; d4 += 4) {
            float4 qa[8], cvv[8];
            #pragma unroll
            for (int i = 0; i < 8; ++i) qa[i] = *(const float4*)&q_lds[(tr + 16 * i) * 132 + d4];
            #pragma unroll
            for (int j = 0; j < 8; ++j) cvv[j] = *(const float4*)&c_lds[(tc + 16 * j) * 132 + d4];
            #pragma unroll
            for (int i = 0; i < 8; ++i)
                #pragma unroll
                for (int j = 0; j < 8; ++j) {
                    acc[i][j] += qa[i].x * cvv[j].x; acc[i][j] += qa[i].y * cvv[j].y;
                    acc[i][j] += qa[i].z * cvv[j].z; acc[i][j] += qa[i].w * cvv[j].w;
                }
        }
        #pragma unroll
        for (int i = 0; i < 8; ++i)
            #pragma unroll
            for (int j = 0; j < 8; ++j) {
                int lp = ch * 128 + tc + 16 * j;
                float dist = cn[m * NPROTO + lp] - 2.0f * acc[i][j];
                if (dist < bestv[i]) { bestv[i] = dist; besti[i] = lp; }
            }
    }

    #pragma unroll
    for (int i = 0; i < 8; ++i) {
        float v = bestv[i]; int ix = besti[i];
        #pragma unroll
        for (int off = 1; off < 16; off <<= 1) {
            float v2 = __shfl_xor(v, off, 64);
            int  ix2 = __shfl_xor(ix, off, 64);
            if (v2 < v || (v2 == v && ix2 < ix)) { v = v2; ix = ix2; }
        }
        bestv[i] = v; besti[i] = ix;
    }

    float lacc = 0.f;
    #pragma unroll
    for (int i = 0; i < 8; ++i) {
        int row = tr + 16 * i;
        int bn  = bn0 + row;
        const float* cvec = cbase + (size_t)besti[i] * DB;
        float* orow = out + (size_t)bn * DM + m * DB;
        #pragma unroll
        for (int h = 0; h < 2; ++h) {
            int colx = h * 64 + tc * 4;
            float4 c4v = *(const float4*)(cvec + colx);
            *(float4*)(orow + colx) = c4v;
            float4 qv2 = *(const float4*)&q_lds[row * 132 + colx];
            float dx = c4v.x - qv2.x, dy = c4v.y - qv2.y;
            float dz = c4v.z - qv2.z, dw = c4v.w - qv2.w;
            lacc += dx * dx + dy * dy + dz * dz + dw * dw;
        }
        if (tc == 0)
            out[(size_t)IDX_OFF + (size_t)bn * NBLK + m] = (float)(m * NPROTO + besti[i]);
    }

    red[t] = lacc;
    __syncthreads();
    for (int s = 128; s > 0; s >>= 1) {
        if (t < s) red[t] += red[t + s];
        __syncthreads();
    }
    if (t == 0) partials[blockIdx.y * gridDim.x + blockIdx.x] = red[0];
}

__global__ __launch_bounds__(256) void vq_final(const float* __restrict__ partials,
                                                float* __restrict__ out, int n) {
    __shared__ float red[256];
    int t = threadIdx.x;
    float v = 0.f;
    for (int i = t; i < n; i += 256) v += partials[i];
    red[t] = v;
    __syncthreads();
    for (int s = 128; s > 0; s >>= 1) {
        if (t < s) red[t] += red[t + s];
        __syncthreads();
    }
    if (t == 0) {
        out[VQ_OFF] = 0.f;
        out[CL_OFF] = red[0] / 8388608.0f;
    }
}

extern "C" void kernel_launch(void* const* d_in, const int* in_sizes, int n_in,
                              void* d_out, int out_size, void* d_ws, size_t ws_size,
                              hipStream_t stream) {
    const float* q   = (const float*)d_in[0];
    const float* mem = (const float*)d_in[1];
    float* out = (float*)d_out;
    char* ws = (char*)d_ws;

    if (ws_size >= (size_t)WS_NEED) {
        u16*   bhp = (u16*)(ws + BH_B);
        u16*   blp = (u16*)(ws + BL_B);
        float* cnp = (float*)(ws + CN_B);
        float* partials = (float*)(ws + PART_B);

        vq_prep<<<128, 256, 0, stream>>>(mem, bhp, blp, cnp);
        dim3 grid(256, 8);
        vq_fused<<<grid, 256, 0, stream>>>(q, mem, bhp, blp, cnp, out, partials);
        vq_final<<<1, 256, 0, stream>>>(partials, out, 2048);
    } else {
        float* cn = (float*)ws;
        float* partials = cn + 4096;
        vq_init<<<16, 256, 0, stream>>>(mem, cn);
        dim3 grid(64, 8);
        vq_main_f32<<<grid, 256, 0, stream>>>(q, mem, cn, out, partials);
        vq_final<<<1, 256, 0, stream>>>(partials, out, 512);
    }
}

// Round 13
// 72.773 us; speedup vs baseline: 1.2097x; 1.2097x over previous
//
#include <hip/hip_runtime.h>

#define NPROTO 512
#define NBLK 8
#define DB 128
#define DM 1024

#define IDX_OFF  8388608
#define VQ_OFF   8454144
#define CL_OFF   8454145

typedef unsigned short u16;
typedef __attribute__((ext_vector_type(8))) _Float16 f16x8;
typedef __attribute__((ext_vector_type(16))) float f32x16;

// ---- ws layout (bytes) ----
#define BH_B   0u
#define BL_B   1048576u
#define CN_B   2097152u
#define PART_B 2113536u
#define WS_NEED (PART_B + 8192u)

// ---- prep: split codes into 2 f16 planes in COALESCED MFMA-operand layout ----
// Bc[pl][m][kst][kg][pm][8]: flat idx = (((m*8+kst)*2+kg)*512 + pm)*8
__global__ __launch_bounds__(256) void vq_prep(const float* __restrict__ src,
                                               u16* __restrict__ hi,
                                               u16* __restrict__ lo,
                                               float* __restrict__ cn) {
    const int t  = threadIdx.x;
    const int p  = blockIdx.x * 32 + (t >> 3);   // global proto 0..4095
    const int g  = t & 7;                        // kst
    const int m  = p >> 9, pm = p & 511;
    const float* s = src + (size_t)p * DB + g * 16;
    float sq = 0.f;
    ushort4 h[4], l[4];
    #pragma unroll
    for (int j = 0; j < 4; ++j) {
        float4 v = *(const float4*)(s + j * 4);
        float x; _Float16 hf;
        #define S1(c, f) x = v.c; hf = (_Float16)x; h[j].f = __builtin_bit_cast(u16, hf); \
            hf = (_Float16)(x - (float)hf); l[j].f = __builtin_bit_cast(u16, hf); sq += x * x;
        S1(x, x) S1(y, y) S1(z, z) S1(w, w)
        #undef S1
    }
    const size_t o0 = ((size_t)((m * 8 + g) * 2 + 0) * 512 + pm) * 8;  // kg=0
    const size_t o1 = ((size_t)((m * 8 + g) * 2 + 1) * 512 + pm) * 8;  // kg=1
    *(uint4*)(hi + o0) = *(uint4*)&h[0];
    *(uint4*)(hi + o1) = *(uint4*)&h[2];
    *(uint4*)(lo + o0) = *(uint4*)&l[0];
    *(uint4*)(lo + o1) = *(uint4*)&l[2];
    sq += __shfl_xor(sq, 1, 64);
    sq += __shfl_xor(sq, 2, 64);
    sq += __shfl_xor(sq, 4, 64);
    if ((t & 7) == 0) cn[p] = sq;
}

__device__ __forceinline__ unsigned cvt2(float x, float y, unsigned& lo) {
    _Float16 hx = (_Float16)x, hy = (_Float16)y;
    _Float16 lx = (_Float16)(x - (float)hx), ly = (_Float16)(y - (float)hy);
    lo = (unsigned)__builtin_bit_cast(u16, lx) | ((unsigned)__builtin_bit_cast(u16, ly) << 16);
    return (unsigned)__builtin_bit_cast(u16, hx) | ((unsigned)__builtin_bit_cast(u16, hy) << 16);
}

// ================= fused MFMA main kernel (A-in-LDS, B-streamed) =============
// r12 post-mortem: (256,4) -> 64-reg budget -> spill (empirical law:
// budget = 256/min_blocks). r13: (256,2) restores 128 budget (84-reg codegen,
// r11-proven); keep Ap[66] padding (conflicts -80%, r12-proven); unroll 2 on
// the chunk loop so chunk c+1's 16 independent L2 loads hoist under chunk c's
// MFMA+fold (the r11 latency hole).
__global__ __launch_bounds__(256, 2) void vq_fused(
        const float* __restrict__ q, const float* __restrict__ mem,
        const u16* __restrict__ bh, const u16* __restrict__ bl,
        const float* __restrict__ cn, float* __restrict__ out,
        float* __restrict__ partials) {
    __shared__ __align__(16) char smem0[16896];   // A_op (padded) / sval overlay
    __shared__ u16  sidxv[4][32][33];
    __shared__ float finalv[4][32];
    __shared__ int   finali[4][32];
    __shared__ float qn_lds[32];
    __shared__ int   bp[32];
    __shared__ float lossbuf[32];

    u16   (*Ap)[8][66][8] = (u16 (*)[8][66][8])smem0;    // [pl][kst][slot][8]
    float (*sval)[32][33] = (float (*)[32][33])smem0;    // overlay after loop

    const int t    = threadIdx.x;
    const int lane = t & 63;
    const int w    = t >> 6;          // 0..3
    const int col  = lane & 31;       // proto col == A row
    const int kg   = lane >> 5;       // k-group (8 elems)
    const int m    = blockIdx.y;
    const int bn0  = blockIdx.x * 32;

    // ---- stage A: 32 rows x 128 d f32 -> 2 f16 planes in lane-order LDS ----
    {
        const int row = t >> 3, g = t & 7;       // g == kst
        const float* src = q + (size_t)(bn0 + row) * DM + m * DB + g * 16;
        float4 v0 = ((const float4*)src)[0];
        float4 v1 = ((const float4*)src)[1];
        float4 v2 = ((const float4*)src)[2];
        float4 v3 = ((const float4*)src)[3];
        float sq = v0.x*v0.x+v0.y*v0.y+v0.z*v0.z+v0.w*v0.w
                 + v1.x*v1.x+v1.y*v1.y+v1.z*v1.z+v1.w*v1.w
                 + v2.x*v2.x+v2.y*v2.y+v2.z*v2.z+v2.w*v2.w
                 + v3.x*v3.x+v3.y*v3.y+v3.z*v3.z+v3.w*v3.w;
        unsigned l0,l1,l2,l3,l4,l5,l6,l7;
        unsigned h0 = cvt2(v0.x, v0.y, l0), h1 = cvt2(v0.z, v0.w, l1);
        unsigned h2 = cvt2(v1.x, v1.y, l2), h3 = cvt2(v1.z, v1.w, l3);
        unsigned h4 = cvt2(v2.x, v2.y, l4), h5 = cvt2(v2.z, v2.w, l5);
        unsigned h6 = cvt2(v3.x, v3.y, l6), h7 = cvt2(v3.z, v3.w, l7);
        // slot row   = kg0 slice (k = g*16 + 0..7)
        // slot row+32= kg1 slice (k = g*16 + 8..15)
        *(uint4*)&Ap[0][g][row][0]      = make_uint4(h0, h1, h2, h3);
        *(uint4*)&Ap[0][g][row + 32][0] = make_uint4(h4, h5, h6, h7);
        *(uint4*)&Ap[1][g][row][0]      = make_uint4(l0, l1, l2, l3);
        *(uint4*)&Ap[1][g][row + 32][0] = make_uint4(l4, l5, l6, l7);
        sq += __shfl_xor(sq, 1, 64);
        sq += __shfl_xor(sq, 2, 64);
        sq += __shfl_xor(sq, 4, 64);
        if (g == 0) qn_lds[row] = sq;
    }
    __syncthreads();

    // ---- main loop: wave w owns protos pbase..pbase+127, 4 chunks of 32 ----
    const int pbase = w * 128;
    const u16* bh_l = bh + ((size_t)(m * 16 + kg) * 512 + pbase + col) * 8;
    const u16* bl_l = bl + ((size_t)(m * 16 + kg) * 512 + pbase + col) * 8;

    float bestv[16]; int besti[16];
    #pragma unroll
    for (int r = 0; r < 16; ++r) { bestv[r] = 3.4e38f; besti[r] = 0; }

    #pragma unroll 2
    for (int c = 0; c < 4; ++c) {
        const float cnv = cn[m * NPROTO + pbase + c * 32 + col];
        const u16* bhc = bh_l + c * 256;
        const u16* blc = bl_l + c * 256;
        f32x16 aA, aB;
        #pragma unroll
        for (int r = 0; r < 16; ++r) { aA[r] = 0.f; aB[r] = 0.f; }
        #pragma unroll
        for (int kst = 0; kst < 8; ++kst) {
            f16x8 Bh = *(const f16x8*)(bhc + kst * 8192);
            f16x8 Bl = *(const f16x8*)(blc + kst * 8192);
            f16x8 Ah = *(const f16x8*)&Ap[0][kst][lane][0];
            f16x8 Al = *(const f16x8*)&Ap[1][kst][lane][0];
            aA = __builtin_amdgcn_mfma_f32_32x32x16_f16(Ah, Bh, aA, 0, 0, 0);
            aB = __builtin_amdgcn_mfma_f32_32x32x16_f16(Al, Bh, aB, 0, 0, 0);
            aB = __builtin_amdgcn_mfma_f32_32x32x16_f16(Ah, Bl, aB, 0, 0, 0);
        }
        const int ix = pbase + c * 32 + col;
        #pragma unroll
        for (int r = 0; r < 16; ++r) {
            float d = cnv - 2.0f * (aA[r] + aB[r]);
            if (d < bestv[r]) { bestv[r] = d; besti[r] = ix; }
        }
    }
    __syncthreads();   // A region now dead -> safe to overlay with sval

    // ---- scatter per-lane bests: C layout row=(r&3)+8*(r>>2)+4*kg, col ----
    #pragma unroll
    for (int r = 0; r < 16; ++r) {
        int row = (r & 3) + 8 * (r >> 2) + 4 * kg;
        sval[w][row][col]  = bestv[r];
        sidxv[w][row][col] = (u16)besti[r];
    }
    __syncthreads();

    // ---- per-wave column reduce ----
    {
        const int rrow = col, seg = kg;
        float bv = 3.4e38f; int bi = 0x7fffffff;
        #pragma unroll
        for (int c2 = 0; c2 < 16; ++c2) {
            float v = sval[w][rrow][seg * 16 + c2];
            int  ix = sidxv[w][rrow][seg * 16 + c2];
            if (v < bv || (v == bv && ix < bi)) { bv = v; bi = ix; }
        }
        float v2 = __shfl_xor(bv, 32, 64);
        int   i2 = __shfl_xor(bi, 32, 64);
        if (v2 < bv || (v2 == bv && i2 < bi)) { bv = v2; bi = i2; }
        if (kg == 0) { finalv[w][rrow] = bv; finali[w][rrow] = bi; }
    }
    __syncthreads();

    // ---- cross-wave combine + publish ----
    if (t < 32) {
        float bv = finalv[0][t]; int bi = finali[0][t];
        #pragma unroll
        for (int w2 = 1; w2 < 4; ++w2) {
            float v2 = finalv[w2][t]; int i2 = finali[w2][t];
            if (v2 < bv || (v2 == bv && i2 < bi)) { bv = v2; bi = i2; }
        }
        bp[t] = bi;
        out[(size_t)IDX_OFF + (size_t)(bn0 + t) * NBLK + m] =
            (float)(m * NPROTO + bi);
        lossbuf[t] = bv + qn_lds[t];   // true dist = qn - 2dot + cn
    }
    __syncthreads();

    // ---- gather winning code rows (exact f32 copy) ----
    {
        const int row = t >> 3, g = t & 7;
        const float* cv = mem + ((size_t)(m * NPROTO + bp[row])) * DB + g * 16;
        float* ov = out + (size_t)(bn0 + row) * DM + m * DB + g * 16;
        ((float4*)ov)[0] = ((const float4*)cv)[0];
        ((float4*)ov)[1] = ((const float4*)cv)[1];
        ((float4*)ov)[2] = ((const float4*)cv)[2];
        ((float4*)ov)[3] = ((const float4*)cv)[3];
    }
    if (t == 0) {
        float s = 0.f;
        #pragma unroll
        for (int i = 0; i < 32; ++i) s += lossbuf[i];
        partials[blockIdx.y * gridDim.x + blockIdx.x] = s;
    }
}

// ================= fallback f32 path (used only if ws too small) =============
__global__ __launch_bounds__(256) void vq_init(const float* __restrict__ mem,
                                               float* __restrict__ cn) {
    int p = blockIdx.x * 256 + threadIdx.x;
    const float* c = mem + (size_t)p * DB;
    float s = 0.f;
    #pragma unroll 8
    for (int k = 0; k < DB; k += 4) {
        float4 v = *(const float4*)(c + k);
        s += v.x * v.x + v.y * v.y + v.z * v.z + v.w * v.w;
    }
    cn[p] = s;
}

__global__ __launch_bounds__(256, 1) void vq_main_f32(const float* __restrict__ q,
                                                      const float* __restrict__ mem,
                                                      const float* __restrict__ cn,
                                                      float* __restrict__ out,
                                                      float* __restrict__ partials) {
    __shared__ float q_lds[128 * 132];
    __shared__ float c_lds[128 * 132];
    __shared__ float red[256];

    const int t    = threadIdx.x;
    const int tile = blockIdx.x;
    const int m    = blockIdx.y;
    const int tr   = t >> 4;
    const int tc   = t & 15;
    const int bn0  = tile * 128;

    const float* qbase = q + (size_t)bn0 * DM + m * DB;
    #pragma unroll
    for (int it = 0; it < 16; ++it) {
        int idx = it * 256 + t;
        int row = idx >> 5;
        int c4  = (idx & 31) << 2;
        *(float4*)&q_lds[row * 132 + c4] = *(const float4*)(qbase + (size_t)row * DM + c4);
    }

    float bestv[8]; int besti[8];
    #pragma unroll
    for (int i = 0; i < 8; ++i) { bestv[i] = 3.4e38f; besti[i] = 0; }
    const float* cbase = mem + (size_t)m * NPROTO * DB;

    for (int ch = 0; ch < 4; ++ch) {
        __syncthreads();
        const float* cb = cbase + (size_t)ch * 128 * DB;
        #pragma unroll
        for (int it = 0; it < 16; ++it) {
            int idx = it * 256 + t;
            int row = idx >> 5;
            int c4  = (idx & 31) << 2;
            *(float4*)&c_lds[row * 132 + c4] = *(const float4*)(cb + row * DB + c4);
        }
        __syncthreads();

        float acc[8][8];
        #pragma unroll
        for (int i = 0; i < 8; ++i)
            #pragma unroll
            for (int j = 0; j < 8; ++j) acc[i][j] = 0.f;

        for (int d4 = 0; d4 < DB; d4 += 4) {
            float4 qa[8], cvv[8];
            #pragma unroll
            for (int i = 0; i < 8; ++i) qa[i] = *(const float4*)&q_lds[(tr + 16 * i) * 132 + d4];
            #pragma unroll
            for (int j = 0; j < 8; ++j) cvv[j] = *(const float4*)&c_lds[(tc + 16 * j) * 132 + d4];
            #pragma unroll
            for (int i = 0; i < 8; ++i)
                #pragma unroll
                for (int j = 0; j < 8; ++j) {
                    acc[i][j] += qa[i].x * cvv[j].x; acc[i][j] += qa[i].y * cvv[j].y;
                    acc[i][j] += qa[i].z * cvv[j].z; acc[i][j] += qa[i].w * cvv[j].w;
                }
        }
        #pragma unroll
        for (int i = 0; i < 8; ++i)
            #pragma unroll
            for (int j = 0; j < 8; ++j) {
                int lp = ch * 128 + tc + 16 * j;
                float dist = cn[m * NPROTO + lp] - 2.0f * acc[i][j];
                if (dist < bestv[i]) { bestv[i] = dist; besti[i] = lp; }
            }
    }

    #pragma unroll
    for (int i = 0; i < 8; ++i) {
        float v = bestv[i]; int ix = besti[i];
        #pragma unroll
        for (int off = 1; off < 16; off <<= 1) {
            float v2 = __shfl_xor(v, off, 64);
            int  ix2 = __shfl_xor(ix, off, 64);
            if (v2 < v || (v2 == v && ix2 < ix)) { v = v2; ix = ix2; }
        }
        bestv[i] = v; besti[i] = ix;
    }

    float lacc = 0.f;
    #pragma unroll
    for (int i = 0; i < 8; ++i) {
        int row = tr + 16 * i;
        int bn  = bn0 + row;
        const float* cvec = cbase + (size_t)besti[i] * DB;
        float* orow = out + (size_t)bn * DM + m * DB;
        #pragma unroll
        for (int h = 0; h < 2; ++h) {
            int colx = h * 64 + tc * 4;
            float4 c4v = *(const float4*)(cvec + colx);
            *(float4*)(orow + colx) = c4v;
            float4 qv2 = *(const float4*)&q_lds[row * 132 + colx];
            float dx = c4v.x - qv2.x, dy = c4v.y - qv2.y;
            float dz = c4v.z - qv2.z, dw = c4v.w - qv2.w;
            lacc += dx * dx + dy * dy + dz * dz + dw * dw;
        }
        if (tc == 0)
            out[(size_t)IDX_OFF + (size_t)bn * NBLK + m] = (float)(m * NPROTO + besti[i]);
    }

    red[t] = lacc;
    __syncthreads();
    for (int s = 128; s > 0; s >>= 1) {
        if (t < s) red[t] += red[t + s];
        __syncthreads();
    }
    if (t == 0) partials[blockIdx.y * gridDim.x + blockIdx.x] = red[0];
}

__global__ __launch_bounds__(256) void vq_final(const float* __restrict__ partials,
                                                float* __restrict__ out, int n) {
    __shared__ float red[256];
    int t = threadIdx.x;
    float v = 0.f;
    for (int i = t; i < n; i += 256) v += partials[i];
    red[t] = v;
    __syncthreads();
    for (int s = 128; s > 0; s >>= 1) {
        if (t < s) red[t] += red[t + s];
        __syncthreads();
    }
    if (t == 0) {
        out[VQ_OFF] = 0.f;
        out[CL_OFF] = red[0] / 8388608.0f;
    }
}

extern "C" void kernel_launch(void* const* d_in, const int* in_sizes, int n_in,
                              void* d_out, int out_size, void* d_ws, size_t ws_size,
                              hipStream_t stream) {
    const float* q   = (const float*)d_in[0];
    const float* mem = (const float*)d_in[1];
    float* out = (float*)d_out;
    char* ws = (char*)d_ws;

    if (ws_size >= (size_t)WS_NEED) {
        u16*   bhp = (u16*)(ws + BH_B);
        u16*   blp = (u16*)(ws + BL_B);
        float* cnp = (float*)(ws + CN_B);
        float* partials = (float*)(ws + PART_B);

        vq_prep<<<128, 256, 0, stream>>>(mem, bhp, blp, cnp);
        dim3 grid(256, 8);
        vq_fused<<<grid, 256, 0, stream>>>(q, mem, bhp, blp, cnp, out, partials);
        vq_final<<<1, 256, 0, stream>>>(partials, out, 2048);
    } else {
        float* cn = (float*)ws;
        float* partials = cn + 4096;
        vq_init<<<16, 256, 0, stream>>>(mem, cn);
        dim3 grid(64, 8);
        vq_main_f32<<<grid, 256, 0, stream>>>(q, mem, cn, out, partials);
        vq_final<<<1, 256, 0, stream>>>(partials, out, 512);
    }
}

// Round 14
// 69.539 us; speedup vs baseline: 1.2659x; 1.0465x over previous
//
#include <hip/hip_runtime.h>

#define NPROTO 512
#define NBLK 8
#define DB 128
#define DM 1024

#define IDX_OFF  8388608
#define VQ_OFF   8454144
#define CL_OFF   8454145

typedef unsigned short u16;
typedef __attribute__((ext_vector_type(8))) _Float16 f16x8;
typedef __attribute__((ext_vector_type(16))) float f32x16;

// ---- ws layout (bytes) ----
#define BH_B   0u
#define BL_B   1048576u
#define CN_B   2097152u
#define PART_B 2113536u
#define WS_NEED (PART_B + 16384u)

// ---- prep: split codes into 2 f16 planes in COALESCED MFMA-operand layout ----
// Bc[pl][m][kst][kg][pm][8]: flat idx = (((m*8+kst)*2+kg)*512 + pm)*8
__global__ __launch_bounds__(256) void vq_prep(const float* __restrict__ src,
                                               u16* __restrict__ hi,
                                               u16* __restrict__ lo,
                                               float* __restrict__ cn) {
    const int t  = threadIdx.x;
    const int p  = blockIdx.x * 32 + (t >> 3);   // global proto 0..4095
    const int g  = t & 7;                        // kst
    const int m  = p >> 9, pm = p & 511;
    const float* s = src + (size_t)p * DB + g * 16;
    float sq = 0.f;
    ushort4 h[4], l[4];
    #pragma unroll
    for (int j = 0; j < 4; ++j) {
        float4 v = *(const float4*)(s + j * 4);
        float x; _Float16 hf;
        #define S1(c, f) x = v.c; hf = (_Float16)x; h[j].f = __builtin_bit_cast(u16, hf); \
            hf = (_Float16)(x - (float)hf); l[j].f = __builtin_bit_cast(u16, hf); sq += x * x;
        S1(x, x) S1(y, y) S1(z, z) S1(w, w)
        #undef S1
    }
    const size_t o0 = ((size_t)((m * 8 + g) * 2 + 0) * 512 + pm) * 8;  // kg=0
    const size_t o1 = ((size_t)((m * 8 + g) * 2 + 1) * 512 + pm) * 8;  // kg=1
    *(uint4*)(hi + o0) = *(uint4*)&h[0];
    *(uint4*)(hi + o1) = *(uint4*)&h[2];
    *(uint4*)(lo + o0) = *(uint4*)&l[0];
    *(uint4*)(lo + o1) = *(uint4*)&l[2];
    sq += __shfl_xor(sq, 1, 64);
    sq += __shfl_xor(sq, 2, 64);
    sq += __shfl_xor(sq, 4, 64);
    if ((t & 7) == 0) cn[p] = sq;
}

__device__ __forceinline__ unsigned cvt2(float x, float y, unsigned& lo) {
    _Float16 hx = (_Float16)x, hy = (_Float16)y;
    _Float16 lx = (_Float16)(x - (float)hx), ly = (_Float16)(y - (float)hy);
    lo = (unsigned)__builtin_bit_cast(u16, lx) | ((unsigned)__builtin_bit_cast(u16, ly) << 16);
    return (unsigned)__builtin_bit_cast(u16, hx) | ((unsigned)__builtin_bit_cast(u16, hy) << 16);
}

// ================= fused MFMA main kernel (wave-private, barrier-free) ======
// r13 post-mortem: 950 GB/s HBM-utilization-bound; 512 MB L2 B-traffic
// (each 32-row block re-streams the full B panel). r14: block = 128 rows,
// wave w owns rows w*32..+31 and loops ALL 512 protos (16 chunks):
//  - B L2 traffic /4 (128 MB) and 4-wave lockstep -> L1 absorbs ~3/4
//  - everything wave-private -> ZERO __syncthreads
//  - per-chunk math bit-identical to r13 -> same indices (absmax 0.0078)
__global__ __launch_bounds__(256, 2) void vq_fused(
        const float* __restrict__ q, const float* __restrict__ mem,
        const u16* __restrict__ bh, const u16* __restrict__ bl,
        const float* __restrict__ cn, float* __restrict__ out,
        float* __restrict__ partials2) {
    __shared__ __align__(16) u16 Ap[4][2][8][66][8];   // per-wave A: 4x16896 B
    __shared__ float qn_lds[128];
    __shared__ int   bp[128];

    const int t    = threadIdx.x;
    const int lane = t & 63;
    const int w    = t >> 6;          // 0..3
    const int col  = lane & 31;
    const int kg   = lane >> 5;
    const int m    = blockIdx.y;
    const int bn0  = blockIdx.x * 128;
    const int rbase = w * 32;

    // ---- stage A (wave-private; no barrier, same-wave LDS dependency) ----
    {
        const int row = lane >> 1;        // 0..31
        const int hf  = lane & 1;         // 64-d half
        const float* src = q + (size_t)(bn0 + rbase + row) * DM + m * DB + hf * 64;
        float sq = 0.f;
        #pragma unroll
        for (int k4 = 0; k4 < 4; ++k4) {
            const int kst = hf * 4 + k4;
            float4 v0 = ((const float4*)(src + k4 * 16))[0];
            float4 v1 = ((const float4*)(src + k4 * 16))[1];
            float4 v2 = ((const float4*)(src + k4 * 16))[2];
            float4 v3 = ((const float4*)(src + k4 * 16))[3];
            sq += v0.x*v0.x+v0.y*v0.y+v0.z*v0.z+v0.w*v0.w
                + v1.x*v1.x+v1.y*v1.y+v1.z*v1.z+v1.w*v1.w
                + v2.x*v2.x+v2.y*v2.y+v2.z*v2.z+v2.w*v2.w
                + v3.x*v3.x+v3.y*v3.y+v3.z*v3.z+v3.w*v3.w;
            unsigned l0,l1,l2,l3,l4,l5,l6,l7;
            unsigned h0 = cvt2(v0.x, v0.y, l0), h1 = cvt2(v0.z, v0.w, l1);
            unsigned h2 = cvt2(v1.x, v1.y, l2), h3 = cvt2(v1.z, v1.w, l3);
            unsigned h4 = cvt2(v2.x, v2.y, l4), h5 = cvt2(v2.z, v2.w, l5);
            unsigned h6 = cvt2(v3.x, v3.y, l6), h7 = cvt2(v3.z, v3.w, l7);
            *(uint4*)&Ap[w][0][kst][row][0]      = make_uint4(h0, h1, h2, h3);
            *(uint4*)&Ap[w][0][kst][row + 32][0] = make_uint4(h4, h5, h6, h7);
            *(uint4*)&Ap[w][1][kst][row][0]      = make_uint4(l0, l1, l2, l3);
            *(uint4*)&Ap[w][1][kst][row + 32][0] = make_uint4(l4, l5, l6, l7);
        }
        sq += __shfl_xor(sq, 1, 64);
        if (hf == 0) qn_lds[rbase + row] = sq;
    }

    // ---- main loop: this wave covers ALL 512 protos in 16 chunks of 32 ----
    const u16* bh_l = bh + ((size_t)(m * 16 + kg) * 512 + col) * 8;
    const u16* bl_l = bl + ((size_t)(m * 16 + kg) * 512 + col) * 8;

    float bestv[16]; int besti[16];
    #pragma unroll
    for (int r = 0; r < 16; ++r) { bestv[r] = 3.4e38f; besti[r] = 0; }

    #pragma unroll 2
    for (int c = 0; c < 16; ++c) {
        const float cnv = cn[m * NPROTO + c * 32 + col];
        const u16* bhc = bh_l + c * 256;
        const u16* blc = bl_l + c * 256;
        f32x16 aA, aB;
        #pragma unroll
        for (int r = 0; r < 16; ++r) { aA[r] = 0.f; aB[r] = 0.f; }
        #pragma unroll
        for (int kst = 0; kst < 8; ++kst) {
            f16x8 Bh = *(const f16x8*)(bhc + kst * 8192);
            f16x8 Bl = *(const f16x8*)(blc + kst * 8192);
            f16x8 Ah = *(const f16x8*)&Ap[w][0][kst][lane][0];
            f16x8 Al = *(const f16x8*)&Ap[w][1][kst][lane][0];
            aA = __builtin_amdgcn_mfma_f32_32x32x16_f16(Ah, Bh, aA, 0, 0, 0);
            aB = __builtin_amdgcn_mfma_f32_32x32x16_f16(Al, Bh, aB, 0, 0, 0);
            aB = __builtin_amdgcn_mfma_f32_32x32x16_f16(Ah, Bl, aB, 0, 0, 0);
        }
        const int ix = c * 32 + col;
        #pragma unroll
        for (int r = 0; r < 16; ++r) {
            float d = cnv - 2.0f * (aA[r] + aB[r]);
            if (d < bestv[r]) { bestv[r] = d; besti[r] = ix; }
        }
    }

    // ---- butterfly argmin across the 32 proto-cols (within 32-lane group) ----
    #pragma unroll
    for (int r = 0; r < 16; ++r) {
        float v = bestv[r]; int ix = besti[r];
        #pragma unroll
        for (int off = 1; off < 32; off <<= 1) {
            float v2 = __shfl_xor(v, off, 64);
            int  ix2 = __shfl_xor(ix, off, 64);
            if (v2 < v || (v2 == v && ix2 < ix)) { v = v2; ix = ix2; }
        }
        bestv[r] = v; besti[r] = ix;
    }

    // ---- publish (lanes col==0 of each kg group; wave-private rows) ----
    if (col == 0) {
        float lp = 0.f;
        #pragma unroll
        for (int r = 0; r < 16; ++r) {
            int row = rbase + (r & 3) + 8 * (r >> 2) + 4 * kg;
            bp[row] = besti[r];
            out[(size_t)IDX_OFF + (size_t)(bn0 + row) * NBLK + m] =
                (float)(m * NPROTO + besti[r]);
            lp += bestv[r] + qn_lds[row];   // true distance for the loss
        }
        partials2[((size_t)blockIdx.y * gridDim.x + blockIdx.x) * 8 + w * 2 + kg] = lp;
    }

    // ---- gather winning code rows (exact f32 copy; same-wave bp) ----
    {
        const int row = lane >> 1, hf = lane & 1;
        const int bpi = bp[rbase + row];
        const float* cv = mem + ((size_t)(m * NPROTO + bpi)) * DB + hf * 64;
        float* ov = out + (size_t)(bn0 + rbase + row) * DM + m * DB + hf * 64;
        #pragma unroll
        for (int j = 0; j < 16; ++j)
            ((float4*)ov)[j] = ((const float4*)cv)[j];
    }
}

// ================= fallback f32 path (used only if ws too small) =============
__global__ __launch_bounds__(256) void vq_init(const float* __restrict__ mem,
                                               float* __restrict__ cn) {
    int p = blockIdx.x * 256 + threadIdx.x;
    const float* c = mem + (size_t)p * DB;
    float s = 0.f;
    #pragma unroll 8
    for (int k = 0; k < DB; k += 4) {
        float4 v = *(const float4*)(c + k);
        s += v.x * v.x + v.y * v.y + v.z * v.z + v.w * v.w;
    }
    cn[p] = s;
}

__global__ __launch_bounds__(256, 1) void vq_main_f32(const float* __restrict__ q,
                                                      const float* __restrict__ mem,
                                                      const float* __restrict__ cn,
                                                      float* __restrict__ out,
                                                      float* __restrict__ partials) {
    __shared__ float q_lds[128 * 132];
    __shared__ float c_lds[128 * 132];
    __shared__ float red[256];

    const int t    = threadIdx.x;
    const int tile = blockIdx.x;
    const int m    = blockIdx.y;
    const int tr   = t >> 4;
    const int tc   = t & 15;
    const int bn0  = tile * 128;

    const float* qbase = q + (size_t)bn0 * DM + m * DB;
    #pragma unroll
    for (int it = 0; it < 16; ++it) {
        int idx = it * 256 + t;
        int row = idx >> 5;
        int c4  = (idx & 31) << 2;
        *(float4*)&q_lds[row * 132 + c4] = *(const float4*)(qbase + (size_t)row * DM + c4);
    }

    float bestv[8]; int besti[8];
    #pragma unroll
    for (int i = 0; i < 8; ++i) { bestv[i] = 3.4e38f; besti[i] = 0; }
    const float* cbase = mem + (size_t)m * NPROTO * DB;

    for (int ch = 0; ch < 4; ++ch) {
        __syncthreads();
        const float* cb = cbase + (size_t)ch * 128 * DB;
        #pragma unroll
        for (int it = 0; it < 16; ++it) {
            int idx = it * 256 + t;
            int row = idx >> 5;
            int c4  = (idx & 31) << 2;
            *(float4*)&c_lds[row * 132 + c4] = *(const float4*)(cb + row * DB + c4);
        }
        __syncthreads();

        float acc[8][8];
        #pragma unroll
        for (int i = 0; i < 8; ++i)
            #pragma unroll
            for (int j = 0; j < 8; ++j) acc[i][j] = 0.f;

        for (int d4 = 0; d4 < DB; d4 += 4) {
            float4 qa[8], cvv[8];
            #pragma unroll
            for (int i = 0; i < 8; ++i) qa[i] = *(const float4*)&q_lds[(tr + 16 * i) * 132 + d4];
            #pragma unroll
            for (int j = 0; j < 8; ++j) cvv[j] = *(const float4*)&c_lds[(tc + 16 * j) * 132 + d4];
            #pragma unroll
            for (int i = 0; i < 8; ++i)
                #pragma unroll
                for (int j = 0; j < 8; ++j) {
                    acc[i][j] += qa[i].x * cvv[j].x; acc[i][j] += qa[i].y * cvv[j].y;
                    acc[i][j] += qa[i].z * cvv[j].z; acc[i][j] += qa[i].w * cvv[j].w;
                }
        }
        #pragma unroll
        for (int i = 0; i < 8; ++i)
            #pragma unroll
            for (int j = 0; j < 8; ++j) {
                int lp = ch * 128 + tc + 16 * j;
                float dist = cn[m * NPROTO + lp] - 2.0f * acc[i][j];
                if (dist < bestv[i]) { bestv[i] = dist; besti[i] = lp; }
            }
    }

    #pragma unroll
    for (int i = 0; i < 8; ++i) {
        float v = bestv[i]; int ix = besti[i];
        #pragma unroll
        for (int off = 1; off < 16; off <<= 1) {
            float v2 = __shfl_xor(v, off, 64);
            int  ix2 = __shfl_xor(ix, off, 64);
            if (v2 < v || (v2 == v && ix2 < ix)) { v = v2; ix = ix2; }
        }
        bestv[i] = v; besti[i] = ix;
    }

    float lacc = 0.f;
    #pragma unroll
    for (int i = 0; i < 8; ++i) {
        int row = tr + 16 * i;
        int bn  = bn0 + row;
        const float* cvec = cbase + (size_t)besti[i] * DB;
        float* orow = out + (size_t)bn * DM + m * DB;
        #pragma unroll
        for (int h = 0; h < 2; ++h) {
            int colx = h * 64 + tc * 4;
            float4 c4v = *(const float4*)(cvec + colx);
            *(float4*)(orow + colx) = c4v;
            float4 qv2 = *(const float4*)&q_lds[row * 132 + colx];
            float dx = c4v.x - qv2.x, dy = c4v.y - qv2.y;
            float dz = c4v.z - qv2.z, dw = c4v.w - qv2.w;
            lacc += dx * dx + dy * dy + dz * dz + dw * dw;
        }
        if (tc == 0)
            out[(size_t)IDX_OFF + (size_t)bn * NBLK + m] = (float)(m * NPROTO + besti[i]);
    }

    red[t] = lacc;
    __syncthreads();
    for (int s = 128; s > 0; s >>= 1) {
        if (t < s) red[t] += red[t + s];
        __syncthreads();
    }
    if (t == 0) partials[blockIdx.y * gridDim.x + blockIdx.x] = red[0];
}

__global__ __launch_bounds__(256) void vq_final(const float* __restrict__ partials,
                                                float* __restrict__ out, int n) {
    __shared__ float red[256];
    int t = threadIdx.x;
    float v = 0.f;
    for (int i = t; i < n; i += 256) v += partials[i];
    red[t] = v;
    __syncthreads();
    for (int s = 128; s > 0; s >>= 1) {
        if (t < s) red[t] += red[t + s];
        __syncthreads();
    }
    if (t == 0) {
        out[VQ_OFF] = 0.f;
        out[CL_OFF] = red[0] / 8388608.0f;
    }
}

extern "C" void kernel_launch(void* const* d_in, const int* in_sizes, int n_in,
                              void* d_out, int out_size, void* d_ws, size_t ws_size,
                              hipStream_t stream) {
    const float* q   = (const float*)d_in[0];
    const float* mem = (const float*)d_in[1];
    float* out = (float*)d_out;
    char* ws = (char*)d_ws;

    if (ws_size >= (size_t)WS_NEED) {
        u16*   bhp = (u16*)(ws + BH_B);
        u16*   blp = (u16*)(ws + BL_B);
        float* cnp = (float*)(ws + CN_B);
        float* partials = (float*)(ws + PART_B);

        vq_prep<<<128, 256, 0, stream>>>(mem, bhp, blp, cnp);
        dim3 grid(64, 8);
        vq_fused<<<grid, 256, 0, stream>>>(q, mem, bhp, blp, cnp, out, partials);
        vq_final<<<1, 256, 0, stream>>>(partials, out, 4096);
    } else {
        float* cn = (float*)ws;
        float* partials = cn + 4096;
        vq_init<<<16, 256, 0, stream>>>(mem, cn);
        dim3 grid(64, 8);
        vq_main_f32<<<grid, 256, 0, stream>>>(q, mem, cn, out, partials);
        vq_final<<<1, 256, 0, stream>>>(partials, out, 512);
    }
}